// Round 1
// baseline (3282.689 us; speedup 1.0000x reference)
//
#include <hip/hip_runtime.h>

#define NEG_SLOPE 0.2f

// ---- ordered-uint encoding for float atomicMax (monotone map) ----
__device__ __forceinline__ unsigned enc_f(float f) {
  unsigned u = __float_as_uint(f);
  return (u & 0x80000000u) ? ~u : (u | 0x80000000u);
}
__device__ __forceinline__ float dec_f(unsigned u) {
  return (u & 0x80000000u) ? __uint_as_float(u & 0x7fffffffu) : __uint_as_float(~u);
}

// ---- prep: wea[0..1] = We1^T @ ae1 ; wea[2..3] = We2^T @ ae2 ----
__global__ void prep_kernel(const float* __restrict__ We1, const float* __restrict__ ae1,
                            const float* __restrict__ We2, const float* __restrict__ ae2,
                            float* __restrict__ outp) {
  int c = threadIdx.x;  // 64 threads
  float a1 = ae1[c], a2 = ae2[c];
  float v0 = We1[c] * a1, v1 = We1[64 + c] * a1;
  float v2 = We2[c] * a2, v3 = We2[64 + c] * a2;
  for (int off = 32; off; off >>= 1) {
    v0 += __shfl_down(v0, off);
    v1 += __shfl_down(v1, off);
    v2 += __shfl_down(v2, off);
    v3 += __shfl_down(v3, off);
  }
  if (c == 0) { outp[0] = v0; outp[1] = v1; outp[2] = v2; outp[3] = v3; }
}

// ---- h = x @ W ; s = h . a_s ; d = h . a_d  (4 nodes / 256-thread block) ----
template <int IN>
__global__ __launch_bounds__(256) void node_linear_scores(
    const float* __restrict__ x, const float* __restrict__ W,
    const float* __restrict__ a_s, const float* __restrict__ a_d,
    float* __restrict__ h, float* __restrict__ s, float* __restrict__ d, int n) {
  __shared__ float xs[4][IN];
  int w = threadIdx.x >> 6, c = threadIdx.x & 63;
  int node = blockIdx.x * 4 + w;
  bool valid = node < n;
  if (valid) {
    for (int k = c; k < IN; k += 64) xs[w][k] = x[(size_t)node * IN + k];
  }
  __syncthreads();
  if (!valid) return;
  float acc = 0.f;
#pragma unroll 8
  for (int k = 0; k < IN; ++k) acc = fmaf(xs[w][k], W[k * 64 + c], acc);
  h[(size_t)node * 64 + c] = acc;
  float sv = acc * a_s[c], dv = acc * a_d[c];
  for (int off = 32; off; off >>= 1) { sv += __shfl_down(sv, off); dv += __shfl_down(dv, off); }
  if (c == 0) { s[node] = sv; d[node] = dv; }
}

// ---- per-edge logit + segment max into menc[dst] ----
__global__ __launch_bounds__(256) void edge_logit_kernel(
    const int* __restrict__ ei, const float* __restrict__ ea,
    const float* __restrict__ s, const float* __restrict__ d,
    const float* __restrict__ wea, float* __restrict__ logit,
    unsigned* __restrict__ menc, int E) {
  int e = blockIdx.x * 256 + threadIdx.x;
  if (e >= E) return;
  int sr = ei[e], ds = ei[E + e];
  float2 eav = *(const float2*)&ea[2 * (size_t)e];
  float l = s[sr] + d[ds] + eav.x * wea[0] + eav.y * wea[1];
  l = l > 0.f ? l : NEG_SLOPE * l;
  logit[e] = l;
  atomicMax(&menc[ds], enc_f(l));
}

// ---- per-edge: ex = exp(logit - m[dst]); acc[dst] += ex*h[src]; den[dst] += ex ----
__global__ __launch_bounds__(256) void edge_accum_kernel(
    const int* __restrict__ ei, const float* __restrict__ logit,
    const unsigned* __restrict__ menc, const float* __restrict__ h,
    float* __restrict__ acc, float* __restrict__ den, int E) {
  int e = blockIdx.x * 4 + (threadIdx.x >> 6);
  if (e >= E) return;
  int c = threadIdx.x & 63;
  int sr = ei[e], ds = ei[E + e];
  float ex = __expf(logit[e] - dec_f(menc[ds]));
  atomicAdd(&acc[(size_t)ds * 64 + c], ex * h[(size_t)sr * 64 + c]);
  if (c == 0) atomicAdd(&den[ds], ex);
}

// ---- y = relu(acc/max(den,1e-16) + bias); reset acc/den/menc for next layer ----
__global__ __launch_bounds__(256) void node_finish_kernel(
    float* __restrict__ acc, float* __restrict__ den, unsigned* __restrict__ menc,
    const float* __restrict__ bias, float* __restrict__ y, int n) {
  int w = threadIdx.x >> 6, c = threadIdx.x & 63;
  int node = blockIdx.x * 4 + w;
  if (node >= n) return;
  float a = acc[(size_t)node * 64 + c];
  float dn = den[node];
  float v = a / fmaxf(dn, 1e-16f) + bias[c];
  y[(size_t)node * 64 + c] = fmaxf(v, 0.f);
  acc[(size_t)node * 64 + c] = 0.f;
  if (c == 0) { den[node] = 0.f; menc[node] = 0u; }
}

// ---- y4 = relu((y0+y1) @ W2 + b2) ----
__global__ __launch_bounds__(256) void node_mlp64_kernel(
    const float* __restrict__ y0, const float* __restrict__ y1,
    const float* __restrict__ W, const float* __restrict__ b,
    float* __restrict__ y4, int n) {
  __shared__ float zs[4][64];
  int w = threadIdx.x >> 6, c = threadIdx.x & 63;
  int node = blockIdx.x * 4 + w;
  bool valid = node < n;
  if (valid) zs[w][c] = y0[(size_t)node * 64 + c] + y1[(size_t)node * 64 + c];
  __syncthreads();
  if (!valid) return;
  float acc = b[c];
#pragma unroll 8
  for (int k = 0; k < 64; ++k) acc = fmaf(zs[w][k], W[k * 64 + c], acc);
  y4[(size_t)node * 64 + c] = fmaxf(acc, 0.f);
}

// ---- one 128->128 relu layer over a 32-edge LDS tile ----
__device__ __forceinline__ void layer128(const float (*__restrict__ in)[128],
                                         float (*__restrict__ out)[128],
                                         const float* __restrict__ W,
                                         const float* __restrict__ b, int t) {
  int c4 = (t & 31) * 4;   // 4 consecutive output columns
  int eb = (t >> 5) * 4;   // 4 edges
  float4 bb = *(const float4*)&b[c4];
  float acc[4][4];
#pragma unroll
  for (int i = 0; i < 4; ++i) {
    acc[i][0] = bb.x; acc[i][1] = bb.y; acc[i][2] = bb.z; acc[i][3] = bb.w;
  }
#pragma unroll 4
  for (int k = 0; k < 128; ++k) {
    float4 wv = *(const float4*)&W[k * 128 + c4];
#pragma unroll
    for (int i = 0; i < 4; ++i) {
      float xv = in[eb + i][k];
      acc[i][0] = fmaf(xv, wv.x, acc[i][0]);
      acc[i][1] = fmaf(xv, wv.y, acc[i][1]);
      acc[i][2] = fmaf(xv, wv.z, acc[i][2]);
      acc[i][3] = fmaf(xv, wv.w, acc[i][3]);
    }
  }
#pragma unroll
  for (int i = 0; i < 4; ++i)
#pragma unroll
    for (int j = 0; j < 4; ++j)
      out[eb + i][c4 + j] = fmaxf(acc[i][j], 0.f);
}

// ---- edge MLP: xb=[y4[src]+y4[dst], relu(ea@We0+be0)]; 4x relu(128x128); 128->145 ----
__global__ __launch_bounds__(256) void edge_mlp_kernel(
    const int* __restrict__ ei, const float* __restrict__ ea,
    const float* __restrict__ y4,
    const float* __restrict__ We0, const float* __restrict__ be0,
    const float* __restrict__ W3, const float* __restrict__ b3,
    const float* __restrict__ Wm0, const float* __restrict__ bm0,
    const float* __restrict__ Wm1, const float* __restrict__ bm1,
    const float* __restrict__ Wm2, const float* __restrict__ bm2,
    const float* __restrict__ W4, const float* __restrict__ b4,
    float* __restrict__ out, int E) {
  __shared__ float bufA[32][128];
  __shared__ float bufB[32][128];
  int t = threadIdx.x;
  int e0 = blockIdx.x * 32;

  for (int idx = t; idx < 32 * 128; idx += 256) {
    int i = idx >> 7, f = idx & 127;
    int e = e0 + i;
    float v = 0.f;
    if (e < E) {
      if (f < 64) {
        int sr = ei[e], ds = ei[E + e];
        v = y4[(size_t)sr * 64 + f] + y4[(size_t)ds * 64 + f];
      } else {
        int cc = f - 64;
        float2 eav = *(const float2*)&ea[2 * (size_t)e];
        v = fmaxf(fmaf(eav.x, We0[cc], fmaf(eav.y, We0[64 + cc], be0[cc])), 0.f);
      }
    }
    bufA[i][f] = v;
  }
  __syncthreads();
  layer128(bufA, bufB, W3, b3, t);   __syncthreads();
  layer128(bufB, bufA, Wm0, bm0, t); __syncthreads();
  layer128(bufA, bufB, Wm1, bm1, t); __syncthreads();
  layer128(bufB, bufA, Wm2, bm2, t); __syncthreads();

  // final 128 -> 145 (no relu)
  int c = t & 31;
  int eb = (t >> 5) * 4;
  float acc[4][5];
#pragma unroll
  for (int j = 0; j < 5; ++j) {
    int col = c + 32 * j;
    float bv = (col < 145) ? b4[col] : 0.f;
#pragma unroll
    for (int i = 0; i < 4; ++i) acc[i][j] = bv;
  }
#pragma unroll 2
  for (int k = 0; k < 128; ++k) {
    float wv[5];
#pragma unroll
    for (int j = 0; j < 5; ++j) {
      int col = c + 32 * j;
      wv[j] = (col < 145) ? W4[k * 145 + col] : 0.f;
    }
#pragma unroll
    for (int i = 0; i < 4; ++i) {
      float xv = bufA[eb + i][k];
#pragma unroll
      for (int j = 0; j < 5; ++j) acc[i][j] = fmaf(xv, wv[j], acc[i][j]);
    }
  }
#pragma unroll
  for (int i = 0; i < 4; ++i) {
    int e = e0 + eb + i;
    if (e < E) {
#pragma unroll
      for (int j = 0; j < 5; ++j) {
        int col = c + 32 * j;
        if (col < 145) out[(size_t)e * 145 + col] = acc[i][j];
      }
    }
  }
}

extern "C" void kernel_launch(void* const* d_in, const int* in_sizes, int n_in,
                              void* d_out, int out_size, void* d_ws, size_t ws_size,
                              hipStream_t stream) {
  const float* x   = (const float*)d_in[0];
  const int*   ei  = (const int*)d_in[1];
  const float* ea  = (const float*)d_in[2];
  const float* Wg1 = (const float*)d_in[4];
  const float* as1 = (const float*)d_in[5];
  const float* ad1 = (const float*)d_in[6];
  const float* We1 = (const float*)d_in[7];
  const float* ae1 = (const float*)d_in[8];
  const float* bg1 = (const float*)d_in[9];
  const float* Wg2 = (const float*)d_in[10];
  const float* as2 = (const float*)d_in[11];
  const float* ad2 = (const float*)d_in[12];
  const float* We2 = (const float*)d_in[13];
  const float* ae2 = (const float*)d_in[14];
  const float* bg2 = (const float*)d_in[15];
  const float* W2  = (const float*)d_in[16];
  const float* b2  = (const float*)d_in[17];
  const float* We0 = (const float*)d_in[18];
  const float* be0 = (const float*)d_in[19];
  const float* W3  = (const float*)d_in[20];
  const float* b3  = (const float*)d_in[21];
  const float* Wm0 = (const float*)d_in[22];
  const float* bm0 = (const float*)d_in[23];
  const float* Wm1 = (const float*)d_in[24];
  const float* bm1 = (const float*)d_in[25];
  const float* Wm2 = (const float*)d_in[26];
  const float* bm2 = (const float*)d_in[27];
  const float* W4  = (const float*)d_in[28];
  const float* b4  = (const float*)d_in[29];
  float* out = (float*)d_out;

  int N = in_sizes[0] / 128;
  int E = in_sizes[1] / 2;

  char* ws = (char*)d_ws;
  size_t off = 0;
  auto alloc = [&](size_t elems) { float* p = (float*)(ws + off); off += elems * 4; return p; };
  float* h     = alloc((size_t)N * 64);
  float* y0    = alloc((size_t)N * 64);
  float* y1    = alloc((size_t)N * 64);
  float* y4    = alloc((size_t)N * 64);
  float* acc   = alloc((size_t)N * 64);   // acc, den, menc contiguous -> single memset
  float* den   = alloc(N);
  unsigned* menc = (unsigned*)alloc(N);
  float* sbuf  = alloc(N);
  float* dbuf  = alloc(N);
  float* logit = alloc(E);
  float* wea   = alloc(4);
  (void)ws_size; (void)n_in; (void)out_size;

  hipMemsetAsync(acc, 0, ((size_t)N * 64 + 2 * (size_t)N) * 4, stream);
  prep_kernel<<<1, 64, 0, stream>>>(We1, ae1, We2, ae2, wea);

  int nb4 = (N + 3) / 4;
  // GAT layer 1
  node_linear_scores<128><<<nb4, 256, 0, stream>>>(x, Wg1, as1, ad1, h, sbuf, dbuf, N);
  edge_logit_kernel<<<(E + 255) / 256, 256, 0, stream>>>(ei, ea, sbuf, dbuf, wea, logit, menc, E);
  edge_accum_kernel<<<(E + 3) / 4, 256, 0, stream>>>(ei, logit, menc, h, acc, den, E);
  node_finish_kernel<<<nb4, 256, 0, stream>>>(acc, den, menc, bg1, y0, N);
  // GAT layer 2
  node_linear_scores<64><<<nb4, 256, 0, stream>>>(y0, Wg2, as2, ad2, h, sbuf, dbuf, N);
  edge_logit_kernel<<<(E + 255) / 256, 256, 0, stream>>>(ei, ea, sbuf, dbuf, wea + 2, logit, menc, E);
  edge_accum_kernel<<<(E + 3) / 4, 256, 0, stream>>>(ei, logit, menc, h, acc, den, E);
  node_finish_kernel<<<nb4, 256, 0, stream>>>(acc, den, menc, bg2, y1, N);
  // node MLP
  node_mlp64_kernel<<<nb4, 256, 0, stream>>>(y0, y1, W2, b2, y4, N);
  // edge MLP (dominant)
  edge_mlp_kernel<<<(E + 31) / 32, 256, 0, stream>>>(
      ei, ea, y4, We0, be0, W3, b3, Wm0, bm0, Wm1, bm1, Wm2, bm2, W4, b4, out, E);
}